// Round 9
// baseline (1055.075 us; speedup 1.0000x reference)
//
#include <hip/hip_runtime.h>
#include <hip/hip_bf16.h>
#include <cstdint>
#include <cstddef>

// ---------------------------------------------------------------------------
// BDH Linear Attention (B=8,N=1024,D=768,H=8,S=3072,HD=384) on gfx950
// Round 9: qkv 256^2 kernel -> BK=32, 2x32KB LDS dbuf (64KB total) => 2
//          blocks/CU so cross-block wave overlap covers the barrier drain
//          (m97/m114 mechanism). Same 2-phase __syncthreads structure.
//          Everything else = r8 (verified: fused y-GEMM, gated q).
// ---------------------------------------------------------------------------

typedef __bf16 bf16_t;
typedef bf16_t bf16x4 __attribute__((ext_vector_type(4)));
typedef bf16_t bf16x8 __attribute__((ext_vector_type(8)));
typedef float f32x4 __attribute__((ext_vector_type(4)));

#define AS1 __attribute__((address_space(1)))
#define AS3 __attribute__((address_space(3)))

// ---------------- 128^2 GEMM mainloop (r3-proven) ---------------------------
__device__ __forceinline__ void gemm128_bt(
    const bf16_t* __restrict__ A, int lda,
    const bf16_t* __restrict__ BT, int ldb,
    int K, int row0, int col0,
    bf16_t* As, bf16_t* Bs, f32x4 acc[4][4])
{
    const int t    = threadIdx.x;
    const int lane = t & 63;
    const int wid  = t >> 6;
    const int wr   = wid >> 1, wc = wid & 1;
    const int fr   = lane & 15;
    const int fk   = (lane >> 4) * 8;

#pragma unroll
    for (int m = 0; m < 4; ++m)
#pragma unroll
        for (int n = 0; n < 4; ++n)
            acc[m][n] = (f32x4){0.f, 0.f, 0.f, 0.f};

    const int rr = lane >> 2;
    const int rc = (lane & 3) * 8;

    for (int k0 = 0; k0 < K; k0 += 32) {
#pragma unroll
        for (int c = 0; c < 2; ++c) {
            const int q = wid * 2 + c;
            __builtin_amdgcn_global_load_lds(
                (const AS1 void*)(A + (size_t)(row0 + q * 16 + rr) * lda + (k0 + rc)),
                (AS3 void*)(As + q * 512), 16, 0, 0);
            __builtin_amdgcn_global_load_lds(
                (const AS1 void*)(BT + (size_t)(col0 + q * 16 + rr) * ldb + (k0 + rc)),
                (AS3 void*)(Bs + q * 512), 16, 0, 0);
        }
        __syncthreads();

        bf16x8 av[4], bv[4];
#pragma unroll
        for (int m = 0; m < 4; ++m)
            av[m] = *(const bf16x8*)&As[(wr * 64 + m * 16 + fr) * 32 + fk];
#pragma unroll
        for (int n = 0; n < 4; ++n)
            bv[n] = *(const bf16x8*)&Bs[(wc * 64 + n * 16 + fr) * 32 + fk];
#pragma unroll
        for (int m = 0; m < 4; ++m)
#pragma unroll
            for (int n = 0; n < 4; ++n)
                acc[m][n] = __builtin_amdgcn_mfma_f32_16x16x32_bf16(av[m], bv[n], acc[m][n], 0, 0, 0);
        __syncthreads();
    }
}

// XCD band remap (r5-proven)
__device__ __forceinline__ void band_map(int flat, int nby, int& bx, int& by)
{
    const int xcd = flat & 7;
    const int seq = flat >> 3;
    const int bandsz = nby >> 3;
    by = xcd * bandsz + (seq % bandsz);
    bx = seq / bandsz;
}

// ---------------- small kernels --------------------------------------------

__global__ void ktrans_w(const float* __restrict__ in, bf16_t* __restrict__ out, int R, int C)
{
    __shared__ float tl[32][33];
    const int c0 = blockIdx.x * 32, r0 = blockIdx.y * 32;
    const int tx = threadIdx.x, ty = threadIdx.y;
#pragma unroll
    for (int i = ty; i < 32; i += 8) tl[i][tx] = in[(size_t)(r0 + i) * C + c0 + tx];
    __syncthreads();
#pragma unroll
    for (int i = ty; i < 32; i += 8) out[(size_t)(c0 + i) * R + r0 + tx] = (bf16_t)tl[tx][i];
}

__device__ __forceinline__ float block_sum256(float v, float* s4)
{
#pragma unroll
    for (int off = 32; off > 0; off >>= 1) v += __shfl_down(v, off);
    const int lane = threadIdx.x & 63, w = threadIdx.x >> 6;
    if (lane == 0) s4[w] = v;
    __syncthreads();
    return s4[0] + s4[1] + s4[2] + s4[3];
}

__global__ void __launch_bounds__(256) kln(
    const float* __restrict__ x, const float* __restrict__ g, const float* __restrict__ bt,
    const float* __restrict__ w_res, const float* __restrict__ b_res,
    bf16_t* __restrict__ xn, float* __restrict__ residue)
{
    __shared__ float red[12];
    const int row = blockIdx.x;
    const float* xr = x + (size_t)row * 768;
    const int t = threadIdx.x;
    const float v0 = xr[t], v1 = xr[t + 256], v2 = xr[t + 512];
    const float ts  = block_sum256(v0 + v1 + v2, red);
    const float ts2 = block_sum256(v0 * v0 + v1 * v1 + v2 * v2, red + 4);
    const float mu  = ts * (1.f / 768.f);
    const float var = ts2 * (1.f / 768.f) - mu * mu;
    const float rs  = rsqrtf(var + 1e-5f);
    float dot = 0.f;
    {
        float xv;
        xv = (v0 - mu) * rs * g[t]       + bt[t];       xn[(size_t)row * 768 + t]       = (bf16_t)xv; dot += xv * w_res[t];
        xv = (v1 - mu) * rs * g[t + 256] + bt[t + 256]; xn[(size_t)row * 768 + t + 256] = (bf16_t)xv; dot += xv * w_res[t + 256];
        xv = (v2 - mu) * rs * g[t + 512] + bt[t + 512]; xn[(size_t)row * 768 + t + 512] = (bf16_t)xv; dot += xv * w_res[t + 512];
    }
    const float td = block_sum256(dot, red + 8);
    if (t == 0) residue[row] = 1.f / (1.f + expf(-(td + b_res[0])));
}

__global__ void kcolmean(const bf16_t* __restrict__ xn, float* __restrict__ xmean)
{
    const int b = blockIdx.x, dc = blockIdx.y, nc = blockIdx.z;
    const int d = dc * 256 + threadIdx.x;
    const bf16_t* p = xn + (size_t)(b * 1024 + nc * 128) * 768 + d;
    float s = 0.f;
#pragma unroll 4
    for (int n = 0; n < 128; ++n) s += (float)p[(size_t)n * 768];
    atomicAdd(&xmean[b * 768 + d], s);
}

// read/write gates + wmean; 256 threads: 64 (b,h) groups x 4 partials
__global__ void __launch_bounds__(256) kgates(
    const float* __restrict__ xmean,
    const float* __restrict__ w_rg, const float* __restrict__ b_rg,
    const float* __restrict__ w_wg, const float* __restrict__ b_wg,
    float* __restrict__ read_g, float* __restrict__ wmean)
{
    __shared__ float pr[64][4], pw[64][4], wg[64];
    const int t = threadIdx.x, grp = t >> 2, qtr = t & 3;
    const int b = grp >> 3, h = grp & 7;
    float dr = 0.f, dw = 0.f;
    for (int d = qtr * 192; d < qtr * 192 + 192; ++d) {
        const float xm = xmean[b * 768 + d] * (1.f / 1024.f);
        dr += xm * w_rg[d * 8 + h];
        dw += xm * w_wg[d * 8 + h];
    }
    pr[grp][qtr] = dr; pw[grp][qtr] = dw;
    __syncthreads();
    if (qtr == 0) {
        const float sr = pr[grp][0] + pr[grp][1] + pr[grp][2] + pr[grp][3];
        const float sw = pw[grp][0] + pw[grp][1] + pw[grp][2] + pw[grp][3];
        read_g[grp] = 1.f / (1.f + expf(-(sr + b_rg[h])));
        wg[grp]     = 1.f / (1.f + expf(-(sw + b_wg[h])));
    }
    __syncthreads();
    if (t < 8) {
        float s = 0.f;
#pragma unroll
        for (int b2 = 0; b2 < 8; ++b2) s += wg[b2 * 8 + t];
        wmean[t] = s * 0.125f;
    }
}

// ---------------- qkv GEMM: 256x256 tile, BK=32, 2x32KB dbuf, 2 blocks/CU ---
// LDS buf (32KB): A [256 rows x 32] at [0,8192), B at [8192,16384) elems.
// Stage: 2 ops x 2 chunks of 128 rows; linear gload_lds, lane x 16B.
// 2-phase: prefetch next-K into other buf, one __syncthreads per K-step;
// co-resident block (2/CU) covers the drain (m97/m114 mechanism).
__global__ void __launch_bounds__(512, 4) kgemm_qkv256(
    const bf16_t* __restrict__ xnc, const bf16_t* __restrict__ w_inT,
    const float* __restrict__ b_in, const float* __restrict__ rg_c,
    bf16_t* __restrict__ qfc, bf16_t* __restrict__ kTc, bf16_t* __restrict__ vTc,
    float* __restrict__ ksum_c, int nrt /* CHUNK*4 row tiles */)
{
    __shared__ __align__(16) bf16_t L[32768];          // 64 KB = 2 bufs
    const int t = threadIdx.x, lane = t & 63, wid = t >> 6;
    const int wr = wid >> 2, wc = wid & 3;             // 2M x 4N waves
    int bx, by;
    band_map(blockIdx.y * 36 + blockIdx.x, nrt, bx, by);
    const int row0 = by * 256, col0 = bx * 256;

    f32x4 acc[8][4];
#pragma unroll
    for (int m = 0; m < 8; ++m)
#pragma unroll
        for (int n = 0; n < 4; ++n)
            acc[m][n] = (f32x4){0.f, 0.f, 0.f, 0.f};

    const int grow = 16 * wid + (lane >> 2);           // row within 128-chunk
    const int gcol = (lane & 3) * 8;                   // elem col 0/8/16/24
    const int ldst = 512 * wid + 8 * lane;             // + 4096*i (elems)

    auto stage = [&](int buf, int k0) {
        bf16_t* base = &L[buf * 16384];
#pragma unroll
        for (int op = 0; op < 2; ++op) {
            const bf16_t* src = op ? w_inT : xnc;
            const int r0 = op ? col0 : row0;
#pragma unroll
            for (int i = 0; i < 2; ++i)
                __builtin_amdgcn_global_load_lds(
                    (const AS1 void*)(src + (size_t)(r0 + 128 * i + grow) * 768 + (k0 + gcol)),
                    (AS3 void*)(base + op * 8192 + i * 4096 + ldst), 16, 0, 0);
        }
    };

    const int fr = lane & 15, fo = (lane >> 4) * 8;

    stage(0, 0);
    __syncthreads();
    int cur = 0;
    for (int k0 = 0; k0 < 768; k0 += 32) {
        if (k0 + 32 < 768) stage(cur ^ 1, k0 + 32);
        const bf16_t* base = &L[cur * 16384];
        bf16x8 bv[4];
#pragma unroll
        for (int n = 0; n < 4; ++n)
            bv[n] = *(const bf16x8*)&base[8192 + (wc * 64 + n * 16 + fr) * 32 + fo];
#pragma unroll
        for (int m = 0; m < 8; ++m) {
            const bf16x8 av = *(const bf16x8*)&base[(wr * 128 + m * 16 + fr) * 32 + fo];
#pragma unroll
            for (int n = 0; n < 4; ++n)
                acc[m][n] = __builtin_amdgcn_mfma_f32_16x16x32_bf16(av, bv[n], acc[m][n], 0, 0, 0);
        }
        __syncthreads();
        cur ^= 1;
    }

    const int third = col0 / 3072;
    const int lb = row0 >> 10;                         // local batch
    if (third == 0) {
        // q path: bias + phi + read-gate scale, row-major store
#pragma unroll
        for (int n2 = 0; n2 < 4; ++n2) {
            const int col  = col0 + wc * 64 + n2 * 16 + fr;
            const int h    = col / 384;
            const float rg = rg_c[lb * 8 + h];
            const float bias = b_in[col];
#pragma unroll
            for (int m = 0; m < 8; ++m) {
#pragma unroll
                for (int r = 0; r < 4; ++r) {
                    const int row = row0 + wr * 128 + m * 16 + (lane >> 4) * 4 + r;
                    const float v = acc[m][n2][r] + bias;
                    const float u = fmaxf(v, 0.f) + 1e-6f;
                    qfc[(size_t)row * 3072 + col] = (bf16_t)(rg * u * sqrtf(u));
                }
            }
        }
    } else {
        // k/v path: bias (+phi for k), transposed store [bh][d][n], ksum atomics
        const int nbb = (row0 & 1023) + wr * 128 + (lane >> 4) * 4;
#pragma unroll
        for (int n2 = 0; n2 < 4; ++n2) {
            const int colg = col0 + wc * 64 + n2 * 16 + fr;
            const int coll = colg - third * 3072;
            const int h = coll / 384, d = coll % 384;
            bf16_t* dstT = ((third == 1) ? kTc : vTc) + (size_t)(lb * 8 + h) * 393216;
            const float bias = b_in[colg];
            float ksp = 0.f;
#pragma unroll
            for (int m = 0; m < 8; ++m) {
                bf16x4 pk;
#pragma unroll
                for (int r = 0; r < 4; ++r) {
                    float v = acc[m][n2][r] + bias;
                    if (third == 1) { const float u = fmaxf(v, 0.f) + 1e-6f; v = u * sqrtf(u); ksp += v; }
                    pk[r] = (bf16_t)v;
                }
                *(bf16x4*)&dstT[(size_t)d * 1024 + nbb + m * 16] = pk;
            }
            if (third == 1) atomicAdd(&ksum_c[(size_t)(lb * 8 + h) * 384 + d], ksp);
        }
    }
}

// state GEMM per local (b,h)
__global__ void __launch_bounds__(256) kgemm_state(
    const bf16_t* __restrict__ kTc, const bf16_t* __restrict__ vTc,
    const float* __restrict__ ksum_c, float* __restrict__ ssum)
{
    __shared__ __align__(16) bf16_t As[4096], Bs[4096];
    const int lbh = blockIdx.z, h = lbh & 7;
    const int row0 = blockIdx.y * 128, col0 = blockIdx.x * 128;
    const bf16_t* A  = kTc + (size_t)lbh * 393216;
    const bf16_t* BT = vTc + (size_t)lbh * 393216;
    f32x4 acc[4][4];
    gemm128_bt(A, 1024, BT, 1024, 1024, row0, col0, As, Bs, acc);

    const int lane = threadIdx.x & 63, wid = threadIdx.x >> 6;
    const int wr = wid >> 1, wc = wid & 1;
    float* ss = ssum + (size_t)h * 147456;
#pragma unroll
    for (int m = 0; m < 4; ++m) {
#pragma unroll
        for (int r = 0; r < 4; ++r) {
            const int d = row0 + wr * 64 + m * 16 + (lane >> 4) * 4 + r;
            const float sc = 1.f / (ksum_c[(size_t)lbh * 384 + d] + 1e-6f);
#pragma unroll
            for (int n = 0; n < 4; ++n) {
                const int e = col0 + wc * 64 + n * 16 + (lane & 15);
                atomicAdd(&ss[(size_t)d * 384 + e], acc[m][n][r] * sc);
            }
        }
    }
}

// mem_new[h,d,e] = bf16(0.95*mem + (0.05*wmean[h]/8)*ssum) — elementwise
__global__ void kmemupd_ew(const float* __restrict__ mem, const float* __restrict__ ssum,
                           const float* __restrict__ wmean, bf16_t* __restrict__ mem_new)
{
    const int idx = blockIdx.x * 256 + threadIdx.x;    // 1179648 total
    const int h = idx / 147456;
    const float wm = wmean[h] * (0.05f / 8.f);
    mem_new[idx] = (bf16_t)(0.95f * mem[idx] + wm * ssum[idx]);
}

// G GEMM: per head, GT[c, h*384+d] = sum_e w_outT[c, h*384+e] * mem_new[h,d,e]
__global__ void __launch_bounds__(256) kgemm_G(
    const bf16_t* __restrict__ w_outT, const bf16_t* __restrict__ mem_new,
    bf16_t* __restrict__ GT)
{
    __shared__ __align__(16) bf16_t As[4096], Bs[4096];
    const int h = blockIdx.z;
    const int row0 = blockIdx.y * 128, col0 = blockIdx.x * 128;   // row=c, col=d
    f32x4 acc[4][4];
    gemm128_bt(w_outT + h * 384, 3072, mem_new + (size_t)h * 147456, 384,
               384, row0, col0, As, Bs, acc);

    const int lane = threadIdx.x & 63, wid = threadIdx.x >> 6;
    const int wr = wid >> 1, wc = wid & 1;
#pragma unroll
    for (int m = 0; m < 4; ++m) {
#pragma unroll
        for (int n = 0; n < 4; ++n) {
            const int d = col0 + wc * 64 + n * 16 + (lane & 15);
#pragma unroll
            for (int r = 0; r < 4; ++r) {
                const int c = row0 + wr * 64 + m * 16 + (lane >> 4) * 4 + r;
                GT[(size_t)c * 3072 + h * 384 + d] = (bf16_t)acc[m][n][r];
            }
        }
    }
}

// out GEMM: C = q~ @ GT^T + b_out; out = residue*C + (1-residue)*x
__global__ void __launch_bounds__(256) kgemm_out(
    const bf16_t* __restrict__ qf, const bf16_t* __restrict__ GT,
    const float* __restrict__ b_out, const float* __restrict__ residue,
    const float* __restrict__ x, float* __restrict__ out)
{
    __shared__ __align__(16) bf16_t As[4096], Bs[4096];
    int bx, by;
    band_map(blockIdx.y * 6 + blockIdx.x, 64, bx, by);
    const int row0 = by * 128, col0 = bx * 128;
    f32x4 acc[4][4];
    gemm128_bt(qf, 3072, GT, 3072, 3072, row0, col0, As, Bs, acc);

    const int lane = threadIdx.x & 63, wid = threadIdx.x >> 6;
    const int wr = wid >> 1, wc = wid & 1;
#pragma unroll
    for (int m = 0; m < 4; ++m) {
#pragma unroll
        for (int n = 0; n < 4; ++n) {
            const int col = col0 + wc * 64 + n * 16 + (lane & 15);
            const float bias = b_out[col];
#pragma unroll
            for (int r = 0; r < 4; ++r) {
                const int row = row0 + wr * 64 + m * 16 + (lane >> 4) * 4 + r;
                const float v = acc[m][n][r] + bias;
                const float rr = residue[row];
                out[(size_t)row * 768 + col] = rr * v + (1.f - rr) * x[(size_t)row * 768 + col];
            }
        }
    }
}

// ---------------------------------------------------------------------------
extern "C" void kernel_launch(void* const* d_in, const int* in_sizes, int n_in,
                              void* d_out, int out_size, void* d_ws, size_t ws_size,
                              hipStream_t stream)
{
    (void)in_sizes; (void)n_in; (void)out_size;
    const float* x     = (const float*)d_in[0];
    const float* mem   = (const float*)d_in[1];
    const float* ln_g  = (const float*)d_in[2];
    const float* ln_b  = (const float*)d_in[3];
    const float* w_in  = (const float*)d_in[4];
    const float* b_in  = (const float*)d_in[5];
    const float* w_out = (const float*)d_in[6];
    const float* b_out = (const float*)d_in[7];
    const float* w_rg  = (const float*)d_in[8];
    const float* b_rg  = (const float*)d_in[9];
    const float* w_wg  = (const float*)d_in[10];
    const float* b_wg  = (const float*)d_in[11];
    const float* w_res = (const float*)d_in[12];
    const float* b_res = (const float*)d_in[13];
    float* out = (float*)d_out;

    auto total_for = [&](int c) -> size_t {
        size_t o = 0;
        auto a = [&](size_t b) { o += (b + 255) & ~(size_t)255; };
        a(50331648);                       // qf
        a(14155776); a(12582912);          // w_inT (GT overlays), xn
        a((size_t)c * 6291456);            // kTc
        a((size_t)c * 6291456);            // vTc
        a(4718592); a(4718592); a(2359296);// w_outT, ssum, mem_new
        a(32768); a(24576); a(98304); a(256); a(256);
        return o;
    };
    int CHUNK = 0;
    for (int c = 8; c >= 2; c >>= 1) if (total_for(c) <= ws_size) { CHUNK = c; break; }
    if (CHUNK == 0) return;                // fail soft

    char* ws = (char*)d_ws;
    size_t off = 0;
    auto alloc = [&](size_t bytes) -> char* {
        char* p = ws + off; off += (bytes + 255) & ~(size_t)255; return p;
    };
    bf16_t* qf      = (bf16_t*)alloc(50331648);
    bf16_t* w_inT   = (bf16_t*)alloc(14155776);
    bf16_t* GT      = w_inT;                 // overlay: w_inT dead after qkv chunks
    bf16_t* xn      = (bf16_t*)alloc(12582912);
    bf16_t* kTc     = (bf16_t*)alloc((size_t)CHUNK * 6291456);
    bf16_t* vTc     = (bf16_t*)alloc((size_t)CHUNK * 6291456);
    bf16_t* w_outT  = (bf16_t*)alloc(4718592);
    float*  ssum    = (float*) alloc(4718592);
    bf16_t* mem_new = (bf16_t*)alloc(2359296);
    float*  residue = (float*) alloc(32768);
    float*  xmean   = (float*) alloc(24576);
    float*  ksum    = (float*) alloc(98304);
    float*  read_g  = (float*) alloc(256);
    float*  wmean   = (float*) alloc(256);

    hipMemsetAsync(xmean, 0, 24576, stream);
    hipMemsetAsync(ksum,  0, 98304, stream);
    hipMemsetAsync(ssum,  0, 4718592, stream);

    ktrans_w<<<dim3(288, 24), dim3(32, 8), 0, stream>>>(w_in, w_inT, 768, 9216);
    ktrans_w<<<dim3(24, 96), dim3(32, 8), 0, stream>>>(w_out, w_outT, 3072, 768);
    kln<<<8192, 256, 0, stream>>>(x, ln_g, ln_b, w_res, b_res, xn, residue);
    kcolmean<<<dim3(8, 3, 8), 256, 0, stream>>>(xn, xmean);
    kgates<<<1, 256, 0, stream>>>(xmean, w_rg, b_rg, w_wg, b_wg, read_g, wmean);

    const int NC = 8 / CHUNK;
    for (int c = 0; c < NC; ++c) {
        const int b0 = c * CHUNK;
        kgemm_qkv256<<<dim3(36, CHUNK * 4), 512, 0, stream>>>(
            xn + (size_t)b0 * 1024 * 768, w_inT, b_in, read_g + b0 * 8,
            qf + (size_t)b0 * 1024 * 3072, kTc, vTc,
            ksum + (size_t)b0 * 8 * 384, CHUNK * 4);
        kgemm_state<<<dim3(3, 3, CHUNK * 8), 256, 0, stream>>>(
            kTc, vTc, ksum + (size_t)b0 * 8 * 384, ssum);
    }

    kmemupd_ew<<<4608, 256, 0, stream>>>(mem, ssum, wmean, mem_new);
    kgemm_G<<<dim3(3, 6, 8), 256, 0, stream>>>(w_outT, mem_new, GT);
    kgemm_out<<<dim3(6, 64), 256, 0, stream>>>(qf, GT, b_out, residue, x, out);
}

// Round 10
// 385.145 us; speedup vs baseline: 2.7394x; 2.7394x over previous
//
#include <hip/hip_runtime.h>
#include <hip/hip_bf16.h>
#include <cstdint>
#include <cstddef>

// ---------------------------------------------------------------------------
// BDH Linear Attention (B=8,N=1024,D=768,H=8,S=3072,HD=384) on gfx950
// Round 10: r8 base (verified 375.6us) + qkv epilogue LDS store-coalescing:
//   - q third: stage [token][feat] tile in LDS, write 512B contiguous rows.
//   - k/v thirds: stage transposed [feat][token] tile with granule-XOR
//     swizzle (g ^= rT&63), readout writes one contiguous 512B row per wave
//     iteration (permuted within the row -> same cache lines).
//   r9's launch_bounds(512,4) spill disaster reverted (keep (512,2)).
// ---------------------------------------------------------------------------

typedef __bf16 bf16_t;
typedef bf16_t bf16x4 __attribute__((ext_vector_type(4)));
typedef bf16_t bf16x8 __attribute__((ext_vector_type(8)));
typedef float f32x4 __attribute__((ext_vector_type(4)));

#define AS1 __attribute__((address_space(1)))
#define AS3 __attribute__((address_space(3)))

// ---------------- 128^2 GEMM mainloop (r3-proven) ---------------------------
__device__ __forceinline__ void gemm128_bt(
    const bf16_t* __restrict__ A, int lda,
    const bf16_t* __restrict__ BT, int ldb,
    int K, int row0, int col0,
    bf16_t* As, bf16_t* Bs, f32x4 acc[4][4])
{
    const int t    = threadIdx.x;
    const int lane = t & 63;
    const int wid  = t >> 6;
    const int wr   = wid >> 1, wc = wid & 1;
    const int fr   = lane & 15;
    const int fk   = (lane >> 4) * 8;

#pragma unroll
    for (int m = 0; m < 4; ++m)
#pragma unroll
        for (int n = 0; n < 4; ++n)
            acc[m][n] = (f32x4){0.f, 0.f, 0.f, 0.f};

    const int rr = lane >> 2;
    const int rc = (lane & 3) * 8;

    for (int k0 = 0; k0 < K; k0 += 32) {
#pragma unroll
        for (int c = 0; c < 2; ++c) {
            const int q = wid * 2 + c;
            __builtin_amdgcn_global_load_lds(
                (const AS1 void*)(A + (size_t)(row0 + q * 16 + rr) * lda + (k0 + rc)),
                (AS3 void*)(As + q * 512), 16, 0, 0);
            __builtin_amdgcn_global_load_lds(
                (const AS1 void*)(BT + (size_t)(col0 + q * 16 + rr) * ldb + (k0 + rc)),
                (AS3 void*)(Bs + q * 512), 16, 0, 0);
        }
        __syncthreads();

        bf16x8 av[4], bv[4];
#pragma unroll
        for (int m = 0; m < 4; ++m)
            av[m] = *(const bf16x8*)&As[(wr * 64 + m * 16 + fr) * 32 + fk];
#pragma unroll
        for (int n = 0; n < 4; ++n)
            bv[n] = *(const bf16x8*)&Bs[(wc * 64 + n * 16 + fr) * 32 + fk];
#pragma unroll
        for (int m = 0; m < 4; ++m)
#pragma unroll
            for (int n = 0; n < 4; ++n)
                acc[m][n] = __builtin_amdgcn_mfma_f32_16x16x32_bf16(av[m], bv[n], acc[m][n], 0, 0, 0);
        __syncthreads();
    }
}

// XCD band remap (r5-proven)
__device__ __forceinline__ void band_map(int flat, int nby, int& bx, int& by)
{
    const int xcd = flat & 7;
    const int seq = flat >> 3;
    const int bandsz = nby >> 3;
    by = xcd * bandsz + (seq % bandsz);
    bx = seq / bandsz;
}

// ---------------- small kernels --------------------------------------------

__global__ void ktrans_w(const float* __restrict__ in, bf16_t* __restrict__ out, int R, int C)
{
    __shared__ float tl[32][33];
    const int c0 = blockIdx.x * 32, r0 = blockIdx.y * 32;
    const int tx = threadIdx.x, ty = threadIdx.y;
#pragma unroll
    for (int i = ty; i < 32; i += 8) tl[i][tx] = in[(size_t)(r0 + i) * C + c0 + tx];
    __syncthreads();
#pragma unroll
    for (int i = ty; i < 32; i += 8) out[(size_t)(c0 + i) * R + r0 + tx] = (bf16_t)tl[tx][i];
}

__device__ __forceinline__ float block_sum256(float v, float* s4)
{
#pragma unroll
    for (int off = 32; off > 0; off >>= 1) v += __shfl_down(v, off);
    const int lane = threadIdx.x & 63, w = threadIdx.x >> 6;
    if (lane == 0) s4[w] = v;
    __syncthreads();
    return s4[0] + s4[1] + s4[2] + s4[3];
}

__global__ void __launch_bounds__(256) kln(
    const float* __restrict__ x, const float* __restrict__ g, const float* __restrict__ bt,
    const float* __restrict__ w_res, const float* __restrict__ b_res,
    bf16_t* __restrict__ xn, float* __restrict__ residue)
{
    __shared__ float red[12];
    const int row = blockIdx.x;
    const float* xr = x + (size_t)row * 768;
    const int t = threadIdx.x;
    const float v0 = xr[t], v1 = xr[t + 256], v2 = xr[t + 512];
    const float ts  = block_sum256(v0 + v1 + v2, red);
    const float ts2 = block_sum256(v0 * v0 + v1 * v1 + v2 * v2, red + 4);
    const float mu  = ts * (1.f / 768.f);
    const float var = ts2 * (1.f / 768.f) - mu * mu;
    const float rs  = rsqrtf(var + 1e-5f);
    float dot = 0.f;
    {
        float xv;
        xv = (v0 - mu) * rs * g[t]       + bt[t];       xn[(size_t)row * 768 + t]       = (bf16_t)xv; dot += xv * w_res[t];
        xv = (v1 - mu) * rs * g[t + 256] + bt[t + 256]; xn[(size_t)row * 768 + t + 256] = (bf16_t)xv; dot += xv * w_res[t + 256];
        xv = (v2 - mu) * rs * g[t + 512] + bt[t + 512]; xn[(size_t)row * 768 + t + 512] = (bf16_t)xv; dot += xv * w_res[t + 512];
    }
    const float td = block_sum256(dot, red + 8);
    if (t == 0) residue[row] = 1.f / (1.f + expf(-(td + b_res[0])));
}

__global__ void kcolmean(const bf16_t* __restrict__ xn, float* __restrict__ xmean)
{
    const int b = blockIdx.x, dc = blockIdx.y, nc = blockIdx.z;
    const int d = dc * 256 + threadIdx.x;
    const bf16_t* p = xn + (size_t)(b * 1024 + nc * 128) * 768 + d;
    float s = 0.f;
#pragma unroll 4
    for (int n = 0; n < 128; ++n) s += (float)p[(size_t)n * 768];
    atomicAdd(&xmean[b * 768 + d], s);
}

// read/write gates + wmean; 256 threads: 64 (b,h) groups x 4 partials
__global__ void __launch_bounds__(256) kgates(
    const float* __restrict__ xmean,
    const float* __restrict__ w_rg, const float* __restrict__ b_rg,
    const float* __restrict__ w_wg, const float* __restrict__ b_wg,
    float* __restrict__ read_g, float* __restrict__ wmean)
{
    __shared__ float pr[64][4], pw[64][4], wg[64];
    const int t = threadIdx.x, grp = t >> 2, qtr = t & 3;
    const int b = grp >> 3, h = grp & 7;
    float dr = 0.f, dw = 0.f;
    for (int d = qtr * 192; d < qtr * 192 + 192; ++d) {
        const float xm = xmean[b * 768 + d] * (1.f / 1024.f);
        dr += xm * w_rg[d * 8 + h];
        dw += xm * w_wg[d * 8 + h];
    }
    pr[grp][qtr] = dr; pw[grp][qtr] = dw;
    __syncthreads();
    if (qtr == 0) {
        const float sr = pr[grp][0] + pr[grp][1] + pr[grp][2] + pr[grp][3];
        const float sw = pw[grp][0] + pw[grp][1] + pw[grp][2] + pw[grp][3];
        read_g[grp] = 1.f / (1.f + expf(-(sr + b_rg[h])));
        wg[grp]     = 1.f / (1.f + expf(-(sw + b_wg[h])));
    }
    __syncthreads();
    if (t < 8) {
        float s = 0.f;
#pragma unroll
        for (int b2 = 0; b2 < 8; ++b2) s += wg[b2 * 8 + t];
        wmean[t] = s * 0.125f;
    }
}

// ---------------- qkv GEMM: 256x256 tile, BK=64, 8 waves, 2-phase dbuf ------
// Main loop = r6/r8 verified. Epilogue: LDS-staged coalesced stores.
__global__ void __launch_bounds__(512, 2) kgemm_qkv256(
    const bf16_t* __restrict__ xnc, const bf16_t* __restrict__ w_inT,
    const float* __restrict__ b_in, const float* __restrict__ rg_c,
    bf16_t* __restrict__ qfc, bf16_t* __restrict__ kTc, bf16_t* __restrict__ vTc,
    float* __restrict__ ksum_c, int nrt /* CHUNK*4 row tiles */)
{
    __shared__ __align__(16) bf16_t L[65536];          // 128 KB, 2 bufs
    const int t = threadIdx.x, lane = t & 63, wid = t >> 6;
    const int wr = wid >> 2, wc = wid & 3;             // 2M x 4N waves
    int bx, by;
    band_map(blockIdx.y * 36 + blockIdx.x, nrt, bx, by);
    const int row0 = by * 256, col0 = bx * 256;

    f32x4 acc[8][4];
#pragma unroll
    for (int m = 0; m < 8; ++m)
#pragma unroll
        for (int n = 0; n < 4; ++n)
            acc[m][n] = (f32x4){0.f, 0.f, 0.f, 0.f};

    const int grow = 16 * wid + (lane >> 2);           // + 128*j
    const int gcol = (lane & 3) * 8;                   // + 32*s
    const int ldst = 512 * wid + 8 * lane;             // + 4096*j + 8192*s

    auto stage = [&](int buf, int k0) {
        bf16_t* base = &L[buf * 32768];
#pragma unroll
        for (int op = 0; op < 2; ++op) {
            const bf16_t* src = op ? w_inT : xnc;
            const int r0 = op ? col0 : row0;
#pragma unroll
            for (int s = 0; s < 2; ++s)
#pragma unroll
                for (int j = 0; j < 2; ++j)
                    __builtin_amdgcn_global_load_lds(
                        (const AS1 void*)(src + (size_t)(r0 + 128 * j + grow) * 768 + (k0 + 32 * s + gcol)),
                        (AS3 void*)(base + op * 16384 + s * 8192 + j * 4096 + ldst),
                        16, 0, 0);
        }
    };

    const int fr = lane & 15, fo = (lane >> 4) * 8;
    const int g4 = lane >> 4;

    stage(0, 0);
    __syncthreads();
    int cur = 0;
    for (int k0 = 0; k0 < 768; k0 += 64) {
        if (k0 + 64 < 768) stage(cur ^ 1, k0 + 64);
        const bf16_t* base = &L[cur * 32768];
#pragma unroll
        for (int s = 0; s < 2; ++s) {
            bf16x8 bv[4];
#pragma unroll
            for (int n = 0; n < 4; ++n)
                bv[n] = *(const bf16x8*)&base[16384 + s * 8192 + (wc * 64 + n * 16 + fr) * 32 + fo];
#pragma unroll
            for (int m = 0; m < 8; ++m) {
                const bf16x8 av = *(const bf16x8*)&base[s * 8192 + (wr * 128 + m * 16 + fr) * 32 + fo];
#pragma unroll
                for (int n = 0; n < 4; ++n)
                    acc[m][n] = __builtin_amdgcn_mfma_f32_16x16x32_bf16(av, bv[n], acc[m][n], 0, 0, 0);
            }
        }
        __syncthreads();
        cur ^= 1;
    }
    // after the final in-loop barrier, all waves are done with L -> reuse it.

    const int third = col0 / 3072;
    const int lb  = row0 >> 10;                        // local batch
    const int nb0 = row0 & 1023;                       // token base in batch

    if (third == 0) {
        // ---- q: bias + phi + gate -> LDS [token 256][feat 256] -> 512B rows
#pragma unroll
        for (int n2 = 0; n2 < 4; ++n2) {
            const int cT  = wc * 64 + n2 * 16 + fr;    // feature-local 0..255
            const int col = col0 + cT;
            const int h   = col / 384;
            const float rg = rg_c[lb * 8 + h];
            const float bias = b_in[col];
#pragma unroll
            for (int m = 0; m < 8; ++m) {
                const int nloc = wr * 128 + m * 16 + g4 * 4;
#pragma unroll
                for (int r = 0; r < 4; ++r) {
                    const float v = acc[m][n2][r] + bias;
                    const float u = fmaxf(v, 0.f) + 1e-6f;
                    L[(nloc + r) * 256 + cT] = (bf16_t)(rg * u * sqrtf(u));
                }
            }
        }
        __syncthreads();
        for (int it = 0; it < 32; ++it) {
            const int nloc = wid * 32 + it;
            const bf16x4 vv = *(const bf16x4*)&L[nloc * 256 + lane * 4];
            *(bf16x4*)&qfc[(size_t)(row0 + nloc) * 3072 + col0 + lane * 4] = vv;
        }
    } else {
        // ---- k/v: transposed [feat][token] tile with granule-XOR swizzle
#pragma unroll
        for (int n2 = 0; n2 < 4; ++n2) {
            const int rT   = wc * 64 + n2 * 16 + fr;   // feature-local 0..255
            const int colg = col0 + rT;
            const int coll = colg - third * 3072;
            const int h = coll / 384, d = coll % 384;
            const float bias = b_in[colg];
            float ksp = 0.f;
#pragma unroll
            for (int m = 0; m < 8; ++m) {
                const int g = wr * 32 + m * 4 + g4;    // token granule 0..63
                bf16x4 pk;
#pragma unroll
                for (int r = 0; r < 4; ++r) {
                    float v = acc[m][n2][r] + bias;
                    if (third == 1) { const float u = fmaxf(v, 0.f) + 1e-6f; v = u * sqrtf(u); ksp += v; }
                    pk[r] = (bf16_t)v;
                }
                *(bf16x4*)&L[rT * 256 + ((g ^ (rT & 63)) << 2)] = pk;
            }
            if (third == 1) atomicAdd(&ksum_c[(size_t)(lb * 8 + h) * 384 + d], ksp);
        }
        __syncthreads();
        bf16_t* dstT0 = (third == 1) ? kTc : vTc;
        for (int it = 0; it < 32; ++it) {
            const int rT = wid * 32 + it;
            const int colg = col0 + rT;
            const int coll = colg - third * 3072;
            const int h = coll / 384, d = coll % 384;
            const bf16x4 vv = *(const bf16x4*)&L[rT * 256 + lane * 4];
            *(bf16x4*)&dstT0[(size_t)(lb * 8 + h) * 393216 + (size_t)d * 1024
                             + nb0 + ((lane ^ (rT & 63)) << 2)] = vv;
        }
    }
}

// state GEMM per local (b,h)
__global__ void __launch_bounds__(256) kgemm_state(
    const bf16_t* __restrict__ kTc, const bf16_t* __restrict__ vTc,
    const float* __restrict__ ksum_c, float* __restrict__ ssum)
{
    __shared__ __align__(16) bf16_t As[4096], Bs[4096];
    const int lbh = blockIdx.z, h = lbh & 7;
    const int row0 = blockIdx.y * 128, col0 = blockIdx.x * 128;
    const bf16_t* A  = kTc + (size_t)lbh * 393216;
    const bf16_t* BT = vTc + (size_t)lbh * 393216;
    f32x4 acc[4][4];
    gemm128_bt(A, 1024, BT, 1024, 1024, row0, col0, As, Bs, acc);

    const int lane = threadIdx.x & 63, wid = threadIdx.x >> 6;
    const int wr = wid >> 1, wc = wid & 1;
    float* ss = ssum + (size_t)h * 147456;
#pragma unroll
    for (int m = 0; m < 4; ++m) {
#pragma unroll
        for (int r = 0; r < 4; ++r) {
            const int d = row0 + wr * 64 + m * 16 + (lane >> 4) * 4 + r;
            const float sc = 1.f / (ksum_c[(size_t)lbh * 384 + d] + 1e-6f);
#pragma unroll
            for (int n = 0; n < 4; ++n) {
                const int e = col0 + wc * 64 + n * 16 + (lane & 15);
                atomicAdd(&ss[(size_t)d * 384 + e], acc[m][n][r] * sc);
            }
        }
    }
}

// mem_new[h,d,e] = bf16(0.95*mem + (0.05*wmean[h]/8)*ssum) — elementwise
__global__ void kmemupd_ew(const float* __restrict__ mem, const float* __restrict__ ssum,
                           const float* __restrict__ wmean, bf16_t* __restrict__ mem_new)
{
    const int idx = blockIdx.x * 256 + threadIdx.x;    // 1179648 total
    const int h = idx / 147456;
    const float wm = wmean[h] * (0.05f / 8.f);
    mem_new[idx] = (bf16_t)(0.95f * mem[idx] + wm * ssum[idx]);
}

// G GEMM: per head, GT[c, h*384+d] = sum_e w_outT[c, h*384+e] * mem_new[h,d,e]
__global__ void __launch_bounds__(256) kgemm_G(
    const bf16_t* __restrict__ w_outT, const bf16_t* __restrict__ mem_new,
    bf16_t* __restrict__ GT)
{
    __shared__ __align__(16) bf16_t As[4096], Bs[4096];
    const int h = blockIdx.z;
    const int row0 = blockIdx.y * 128, col0 = blockIdx.x * 128;   // row=c, col=d
    f32x4 acc[4][4];
    gemm128_bt(w_outT + h * 384, 3072, mem_new + (size_t)h * 147456, 384,
               384, row0, col0, As, Bs, acc);

    const int lane = threadIdx.x & 63, wid = threadIdx.x >> 6;
    const int wr = wid >> 1, wc = wid & 1;
#pragma unroll
    for (int m = 0; m < 4; ++m) {
#pragma unroll
        for (int n = 0; n < 4; ++n) {
            const int d = col0 + wc * 64 + n * 16 + (lane & 15);
#pragma unroll
            for (int r = 0; r < 4; ++r) {
                const int c = row0 + wr * 64 + m * 16 + (lane >> 4) * 4 + r;
                GT[(size_t)c * 3072 + h * 384 + d] = (bf16_t)acc[m][n][r];
            }
        }
    }
}

// out GEMM: C = q~ @ GT^T + b_out; out = residue*C + (1-residue)*x
__global__ void __launch_bounds__(256) kgemm_out(
    const bf16_t* __restrict__ qf, const bf16_t* __restrict__ GT,
    const float* __restrict__ b_out, const float* __restrict__ residue,
    const float* __restrict__ x, float* __restrict__ out)
{
    __shared__ __align__(16) bf16_t As[4096], Bs[4096];
    int bx, by;
    band_map(blockIdx.y * 6 + blockIdx.x, 64, bx, by);
    const int row0 = by * 128, col0 = bx * 128;
    f32x4 acc[4][4];
    gemm128_bt(qf, 3072, GT, 3072, 3072, row0, col0, As, Bs, acc);

    const int lane = threadIdx.x & 63, wid = threadIdx.x >> 6;
    const int wr = wid >> 1, wc = wid & 1;
#pragma unroll
    for (int m = 0; m < 4; ++m) {
#pragma unroll
        for (int n = 0; n < 4; ++n) {
            const int col = col0 + wc * 64 + n * 16 + (lane & 15);
            const float bias = b_out[col];
#pragma unroll
            for (int r = 0; r < 4; ++r) {
                const int row = row0 + wr * 64 + m * 16 + (lane >> 4) * 4 + r;
                const float v = acc[m][n][r] + bias;
                const float rr = residue[row];
                out[(size_t)row * 768 + col] = rr * v + (1.f - rr) * x[(size_t)row * 768 + col];
            }
        }
    }
}

// ---------------------------------------------------------------------------
extern "C" void kernel_launch(void* const* d_in, const int* in_sizes, int n_in,
                              void* d_out, int out_size, void* d_ws, size_t ws_size,
                              hipStream_t stream)
{
    (void)in_sizes; (void)n_in; (void)out_size;
    const float* x     = (const float*)d_in[0];
    const float* mem   = (const float*)d_in[1];
    const float* ln_g  = (const float*)d_in[2];
    const float* ln_b  = (const float*)d_in[3];
    const float* w_in  = (const float*)d_in[4];
    const float* b_in  = (const float*)d_in[5];
    const float* w_out = (const float*)d_in[6];
    const float* b_out = (const float*)d_in[7];
    const float* w_rg  = (const float*)d_in[8];
    const float* b_rg  = (const float*)d_in[9];
    const float* w_wg  = (const float*)d_in[10];
    const float* b_wg  = (const float*)d_in[11];
    const float* w_res = (const float*)d_in[12];
    const float* b_res = (const float*)d_in[13];
    float* out = (float*)d_out;

    auto total_for = [&](int c) -> size_t {
        size_t o = 0;
        auto a = [&](size_t b) { o += (b + 255) & ~(size_t)255; };
        a(50331648);                       // qf
        a(14155776); a(12582912);          // w_inT (GT overlays), xn
        a((size_t)c * 6291456);            // kTc
        a((size_t)c * 6291456);            // vTc
        a(4718592); a(4718592); a(2359296);// w_outT, ssum, mem_new
        a(32768); a(24576); a(98304); a(256); a(256);
        return o;
    };
    int CHUNK = 0;
    for (int c = 8; c >= 2; c >>= 1) if (total_for(c) <= ws_size) { CHUNK = c; break; }
    if (CHUNK == 0) return;                // fail soft

    char* ws = (char*)d_ws;
    size_t off = 0;
    auto alloc = [&](size_t bytes) -> char* {
        char* p = ws + off; off += (bytes + 255) & ~(size_t)255; return p;
    };
    bf16_t* qf      = (bf16_t*)alloc(50331648);
    bf16_t* w_inT   = (bf16_t*)alloc(14155776);
    bf16_t* GT      = w_inT;                 // overlay: w_inT dead after qkv chunks
    bf16_t* xn      = (bf16_t*)alloc(12582912);
    bf16_t* kTc     = (bf16_t*)alloc((size_t)CHUNK * 6291456);
    bf16_t* vTc     = (bf16_t*)alloc((size_t)CHUNK * 6291456);
    bf16_t* w_outT  = (bf16_t*)alloc(4718592);
    float*  ssum    = (float*) alloc(4718592);
    bf16_t* mem_new = (bf16_t*)alloc(2359296);
    float*  residue = (float*) alloc(32768);
    float*  xmean   = (float*) alloc(24576);
    float*  ksum    = (float*) alloc(98304);
    float*  read_g  = (float*) alloc(256);
    float*  wmean   = (float*) alloc(256);

    hipMemsetAsync(xmean, 0, 24576, stream);
    hipMemsetAsync(ksum,  0, 98304, stream);
    hipMemsetAsync(ssum,  0, 4718592, stream);

    ktrans_w<<<dim3(288, 24), dim3(32, 8), 0, stream>>>(w_in, w_inT, 768, 9216);
    ktrans_w<<<dim3(24, 96), dim3(32, 8), 0, stream>>>(w_out, w_outT, 3072, 768);
    kln<<<8192, 256, 0, stream>>>(x, ln_g, ln_b, w_res, b_res, xn, residue);
    kcolmean<<<dim3(8, 3, 8), 256, 0, stream>>>(xn, xmean);
    kgates<<<1, 256, 0, stream>>>(xmean, w_rg, b_rg, w_wg, b_wg, read_g, wmean);

    const int NC = 8 / CHUNK;
    for (int c = 0; c < NC; ++c) {
        const int b0 = c * CHUNK;
        kgemm_qkv256<<<dim3(36, CHUNK * 4), 512, 0, stream>>>(
            xn + (size_t)b0 * 1024 * 768, w_inT, b_in, read_g + b0 * 8,
            qf + (size_t)b0 * 1024 * 3072, kTc, vTc,
            ksum + (size_t)b0 * 8 * 384, CHUNK * 4);
        kgemm_state<<<dim3(3, 3, CHUNK * 8), 256, 0, stream>>>(
            kTc, vTc, ksum + (size_t)b0 * 8 * 384, ssum);
    }

    kmemupd_ew<<<4608, 256, 0, stream>>>(mem, ssum, wmean, mem_new);
    kgemm_G<<<dim3(3, 6, 8), 256, 0, stream>>>(w_outT, mem_new, GT);
    kgemm_out<<<dim3(6, 64), 256, 0, stream>>>(qf, GT, b_out, residue, x, out);
}

// Round 11
// 368.533 us; speedup vs baseline: 2.8629x; 1.0451x over previous
//
#include <hip/hip_runtime.h>
#include <hip/hip_bf16.h>
#include <cstdint>
#include <cstddef>

// ---------------------------------------------------------------------------
// BDH Linear Attention (B=8,N=1024,D=768,H=8,S=3072,HD=384) on gfx950
// Round 11: r8 base; qkv mainloop = 4-buf BK=32 counted-vmcnt (r7-verified
//   sync + swizzle) PLUS register double-banking: pre-read tile t+1 frags
//   while tile t MFMAs run; ONE barrier per K-step; vmcnt taper 8/4/0.
//   Named reg banks (no runtime indexing), 2x-unrolled loop.
// ---------------------------------------------------------------------------

typedef __bf16 bf16_t;
typedef bf16_t bf16x4 __attribute__((ext_vector_type(4)));
typedef bf16_t bf16x8 __attribute__((ext_vector_type(8)));
typedef float f32x4 __attribute__((ext_vector_type(4)));

#define AS1 __attribute__((address_space(1)))
#define AS3 __attribute__((address_space(3)))

// ---------------- 128^2 GEMM mainloop (r3-proven) ---------------------------
__device__ __forceinline__ void gemm128_bt(
    const bf16_t* __restrict__ A, int lda,
    const bf16_t* __restrict__ BT, int ldb,
    int K, int row0, int col0,
    bf16_t* As, bf16_t* Bs, f32x4 acc[4][4])
{
    const int t    = threadIdx.x;
    const int lane = t & 63;
    const int wid  = t >> 6;
    const int wr   = wid >> 1, wc = wid & 1;
    const int fr   = lane & 15;
    const int fk   = (lane >> 4) * 8;

#pragma unroll
    for (int m = 0; m < 4; ++m)
#pragma unroll
        for (int n = 0; n < 4; ++n)
            acc[m][n] = (f32x4){0.f, 0.f, 0.f, 0.f};

    const int rr = lane >> 2;
    const int rc = (lane & 3) * 8;

    for (int k0 = 0; k0 < K; k0 += 32) {
#pragma unroll
        for (int c = 0; c < 2; ++c) {
            const int q = wid * 2 + c;
            __builtin_amdgcn_global_load_lds(
                (const AS1 void*)(A + (size_t)(row0 + q * 16 + rr) * lda + (k0 + rc)),
                (AS3 void*)(As + q * 512), 16, 0, 0);
            __builtin_amdgcn_global_load_lds(
                (const AS1 void*)(BT + (size_t)(col0 + q * 16 + rr) * ldb + (k0 + rc)),
                (AS3 void*)(Bs + q * 512), 16, 0, 0);
        }
        __syncthreads();

        bf16x8 av[4], bv[4];
#pragma unroll
        for (int m = 0; m < 4; ++m)
            av[m] = *(const bf16x8*)&As[(wr * 64 + m * 16 + fr) * 32 + fk];
#pragma unroll
        for (int n = 0; n < 4; ++n)
            bv[n] = *(const bf16x8*)&Bs[(wc * 64 + n * 16 + fr) * 32 + fk];
#pragma unroll
        for (int m = 0; m < 4; ++m)
#pragma unroll
            for (int n = 0; n < 4; ++n)
                acc[m][n] = __builtin_amdgcn_mfma_f32_16x16x32_bf16(av[m], bv[n], acc[m][n], 0, 0, 0);
        __syncthreads();
    }
}

// XCD band remap (r5-proven)
__device__ __forceinline__ void band_map(int flat, int nby, int& bx, int& by)
{
    const int xcd = flat & 7;
    const int seq = flat >> 3;
    const int bandsz = nby >> 3;
    by = xcd * bandsz + (seq % bandsz);
    bx = seq / bandsz;
}

// ---------------- small kernels --------------------------------------------

__global__ void ktrans_w(const float* __restrict__ in, bf16_t* __restrict__ out, int R, int C)
{
    __shared__ float tl[32][33];
    const int c0 = blockIdx.x * 32, r0 = blockIdx.y * 32;
    const int tx = threadIdx.x, ty = threadIdx.y;
#pragma unroll
    for (int i = ty; i < 32; i += 8) tl[i][tx] = in[(size_t)(r0 + i) * C + c0 + tx];
    __syncthreads();
#pragma unroll
    for (int i = ty; i < 32; i += 8) out[(size_t)(c0 + i) * R + r0 + tx] = (bf16_t)tl[tx][i];
}

__device__ __forceinline__ float block_sum256(float v, float* s4)
{
#pragma unroll
    for (int off = 32; off > 0; off >>= 1) v += __shfl_down(v, off);
    const int lane = threadIdx.x & 63, w = threadIdx.x >> 6;
    if (lane == 0) s4[w] = v;
    __syncthreads();
    return s4[0] + s4[1] + s4[2] + s4[3];
}

__global__ void __launch_bounds__(256) kln(
    const float* __restrict__ x, const float* __restrict__ g, const float* __restrict__ bt,
    const float* __restrict__ w_res, const float* __restrict__ b_res,
    bf16_t* __restrict__ xn, float* __restrict__ residue)
{
    __shared__ float red[12];
    const int row = blockIdx.x;
    const float* xr = x + (size_t)row * 768;
    const int t = threadIdx.x;
    const float v0 = xr[t], v1 = xr[t + 256], v2 = xr[t + 512];
    const float ts  = block_sum256(v0 + v1 + v2, red);
    const float ts2 = block_sum256(v0 * v0 + v1 * v1 + v2 * v2, red + 4);
    const float mu  = ts * (1.f / 768.f);
    const float var = ts2 * (1.f / 768.f) - mu * mu;
    const float rs  = rsqrtf(var + 1e-5f);
    float dot = 0.f;
    {
        float xv;
        xv = (v0 - mu) * rs * g[t]       + bt[t];       xn[(size_t)row * 768 + t]       = (bf16_t)xv; dot += xv * w_res[t];
        xv = (v1 - mu) * rs * g[t + 256] + bt[t + 256]; xn[(size_t)row * 768 + t + 256] = (bf16_t)xv; dot += xv * w_res[t + 256];
        xv = (v2 - mu) * rs * g[t + 512] + bt[t + 512]; xn[(size_t)row * 768 + t + 512] = (bf16_t)xv; dot += xv * w_res[t + 512];
    }
    const float td = block_sum256(dot, red + 8);
    if (t == 0) residue[row] = 1.f / (1.f + expf(-(td + b_res[0])));
}

__global__ void kcolmean(const bf16_t* __restrict__ xn, float* __restrict__ xmean)
{
    const int b = blockIdx.x, dc = blockIdx.y, nc = blockIdx.z;
    const int d = dc * 256 + threadIdx.x;
    const bf16_t* p = xn + (size_t)(b * 1024 + nc * 128) * 768 + d;
    float s = 0.f;
#pragma unroll 4
    for (int n = 0; n < 128; ++n) s += (float)p[(size_t)n * 768];
    atomicAdd(&xmean[b * 768 + d], s);
}

// read/write gates + wmean; 256 threads: 64 (b,h) groups x 4 partials
__global__ void __launch_bounds__(256) kgates(
    const float* __restrict__ xmean,
    const float* __restrict__ w_rg, const float* __restrict__ b_rg,
    const float* __restrict__ w_wg, const float* __restrict__ b_wg,
    float* __restrict__ read_g, float* __restrict__ wmean)
{
    __shared__ float pr[64][4], pw[64][4], wg[64];
    const int t = threadIdx.x, grp = t >> 2, qtr = t & 3;
    const int b = grp >> 3, h = grp & 7;
    float dr = 0.f, dw = 0.f;
    for (int d = qtr * 192; d < qtr * 192 + 192; ++d) {
        const float xm = xmean[b * 768 + d] * (1.f / 1024.f);
        dr += xm * w_rg[d * 8 + h];
        dw += xm * w_wg[d * 8 + h];
    }
    pr[grp][qtr] = dr; pw[grp][qtr] = dw;
    __syncthreads();
    if (qtr == 0) {
        const float sr = pr[grp][0] + pr[grp][1] + pr[grp][2] + pr[grp][3];
        const float sw = pw[grp][0] + pw[grp][1] + pw[grp][2] + pw[grp][3];
        read_g[grp] = 1.f / (1.f + expf(-(sr + b_rg[h])));
        wg[grp]     = 1.f / (1.f + expf(-(sw + b_wg[h])));
    }
    __syncthreads();
    if (t < 8) {
        float s = 0.f;
#pragma unroll
        for (int b2 = 0; b2 < 8; ++b2) s += wg[b2 * 8 + t];
        wmean[t] = s * 0.125f;
    }
}

// ---------------- qkv GEMM: 256x256, BK=32, 4-buf, reg-double-banked --------
// LDS: 4 bufs x 32KB (A 8192 elems + B 8192 elems each); slot swizzle
// phys = logical ^ ((row>>1)&3), staged via inverse-permuted global source
// (r7 HW-verified). Per iter: vmcnt(taper) -> s_barrier -> ds_read(t+1) into
// alternate reg bank || stage(t+4) || MFMA(current bank) -> lgkmcnt(0).
__global__ void __launch_bounds__(512) kgemm_qkv256(
    const bf16_t* __restrict__ xnc, const bf16_t* __restrict__ w_inT,
    const float* __restrict__ b_in, const float* __restrict__ rg_c,
    bf16_t* __restrict__ qfc, bf16_t* __restrict__ kTc, bf16_t* __restrict__ vTc,
    float* __restrict__ ksum_c, int nrt /* CHUNK*4 row tiles */)
{
    __shared__ __align__(16) bf16_t L[65536];          // 128 KB = 4 bufs
    const int t = threadIdx.x, lane = t & 63, wid = t >> 6;
    const int wr = wid >> 2, wc = wid & 3;             // 2M x 4N waves
    int bx, by;
    band_map(blockIdx.y * 36 + blockIdx.x, nrt, bx, by);
    const int row0 = by * 256, col0 = bx * 256;

    f32x4 acc[8][4];
#pragma unroll
    for (int m = 0; m < 8; ++m)
#pragma unroll
        for (int n = 0; n < 4; ++n)
            acc[m][n] = (f32x4){0.f, 0.f, 0.f, 0.f};

    // staging constants (r7-verified): inverse slot swizzle on global source
    const int sgrow = wid * 16 + (lane >> 2);                       // + i*128
    const int sgcol = (((lane & 3) ^ ((lane >> 3) & 3)) * 8);
    // read swizzle (r7-verified): phys elem add = (lslot ^ ((row>>1)&3))*8
    const int xslot = (((lane >> 4) ^ ((lane >> 1) & 3))) * 8;
    const int fr = lane & 15;

    auto stage = [&](int buf, int k0) {
        bf16_t* base = &L[buf * 16384];
#pragma unroll
        for (int op = 0; op < 2; ++op) {
            const bf16_t* src = op ? w_inT : xnc;
            const int r0 = op ? col0 : row0;
#pragma unroll
            for (int i = 0; i < 2; ++i)
                __builtin_amdgcn_global_load_lds(
                    (const AS1 void*)(src + (size_t)(r0 + i * 128 + sgrow) * 768 + (k0 + sgcol)),
                    (AS3 void*)(base + op * 8192 + i * 4096 + wid * 512), 16, 0, 0);
        }
    };

    bf16x8 avA[8], bvA[4], avB[8], bvB[4];
    auto ldfrags = [&](int buf, bf16x8 (&av)[8], bf16x8 (&bv)[4]) {
        const bf16_t* base = &L[buf * 16384];
#pragma unroll
        for (int n = 0; n < 4; ++n)
            bv[n] = *(const bf16x8*)&base[8192 + (wc * 64 + n * 16 + fr) * 32 + xslot];
#pragma unroll
        for (int m = 0; m < 8; ++m)
            av[m] = *(const bf16x8*)&base[(wr * 128 + m * 16 + fr) * 32 + xslot];
    };

    // prologue: 4 tiles in flight; preload tile 0 fragments into bank A
    stage(0, 0); stage(1, 32); stage(2, 64); stage(3, 96);
    asm volatile("s_waitcnt vmcnt(12)" ::: "memory");
    __builtin_amdgcn_s_barrier();
    __builtin_amdgcn_sched_barrier(0);
    ldfrags(0, avA, bvA);
    asm volatile("s_waitcnt lgkmcnt(0)" ::: "memory");

    const int NT = 24;
    auto body = [&](int ti, bf16x8 (&avc)[8], bf16x8 (&bvc)[4],
                            bf16x8 (&avn)[8], bf16x8 (&bvn)[4]) {
        if (ti < NT - 1) {
            if (ti <= 20)      asm volatile("s_waitcnt vmcnt(8)" ::: "memory");
            else if (ti == 21) asm volatile("s_waitcnt vmcnt(4)" ::: "memory");
            else               asm volatile("s_waitcnt vmcnt(0)" ::: "memory");
            __builtin_amdgcn_s_barrier();
            __builtin_amdgcn_sched_barrier(0);
            ldfrags((ti + 1) & 3, avn, bvn);           // pre-read next tile
            if (ti + 4 < NT) stage(ti & 3, (ti + 4) * 32);
        }
        __builtin_amdgcn_s_setprio(1);
#pragma unroll
        for (int m = 0; m < 8; ++m)
#pragma unroll
            for (int n = 0; n < 4; ++n)
                acc[m][n] = __builtin_amdgcn_mfma_f32_16x16x32_bf16(avc[m], bvc[n], acc[m][n], 0, 0, 0);
        __builtin_amdgcn_s_setprio(0);
        if (ti < NT - 1) asm volatile("s_waitcnt lgkmcnt(0)" ::: "memory");
    };

    for (int tt = 0; tt < NT; tt += 2) {
        body(tt,     avA, bvA, avB, bvB);
        body(tt + 1, avB, bvB, avA, bvA);
    }

    // ---- epilogue (r8 verbatim) ----
    const int third = col0 / 3072;
    const int lb = row0 >> 10;                         // local batch
    if (third == 0) {
        // q path: bias + phi + read-gate scale, row-major store
#pragma unroll
        for (int n2 = 0; n2 < 4; ++n2) {
            const int col  = col0 + wc * 64 + n2 * 16 + fr;
            const int h    = col / 384;
            const float rg = rg_c[lb * 8 + h];
            const float bias = b_in[col];
#pragma unroll
            for (int m = 0; m < 8; ++m) {
#pragma unroll
                for (int r = 0; r < 4; ++r) {
                    const int row = row0 + wr * 128 + m * 16 + (lane >> 4) * 4 + r;
                    const float v = acc[m][n2][r] + bias;
                    const float u = fmaxf(v, 0.f) + 1e-6f;
                    qfc[(size_t)row * 3072 + col] = (bf16_t)(rg * u * sqrtf(u));
                }
            }
        }
    } else {
        // k/v path: bias (+phi for k), transposed store [bh][d][n], ksum atomics
        const int nbb = (row0 & 1023) + wr * 128 + (lane >> 4) * 4;
#pragma unroll
        for (int n2 = 0; n2 < 4; ++n2) {
            const int colg = col0 + wc * 64 + n2 * 16 + fr;
            const int coll = colg - third * 3072;
            const int h = coll / 384, d = coll % 384;
            bf16_t* dstT = ((third == 1) ? kTc : vTc) + (size_t)(lb * 8 + h) * 393216;
            const float bias = b_in[colg];
            float ksp = 0.f;
#pragma unroll
            for (int m = 0; m < 8; ++m) {
                bf16x4 pk;
#pragma unroll
                for (int r = 0; r < 4; ++r) {
                    float v = acc[m][n2][r] + bias;
                    if (third == 1) { const float u = fmaxf(v, 0.f) + 1e-6f; v = u * sqrtf(u); ksp += v; }
                    pk[r] = (bf16_t)v;
                }
                *(bf16x4*)&dstT[(size_t)d * 1024 + nbb + m * 16] = pk;
            }
            if (third == 1) atomicAdd(&ksum_c[(size_t)(lb * 8 + h) * 384 + d], ksp);
        }
    }
}

// state GEMM per local (b,h)
__global__ void __launch_bounds__(256) kgemm_state(
    const bf16_t* __restrict__ kTc, const bf16_t* __restrict__ vTc,
    const float* __restrict__ ksum_c, float* __restrict__ ssum)
{
    __shared__ __align__(16) bf16_t As[4096], Bs[4096];
    const int lbh = blockIdx.z, h = lbh & 7;
    const int row0 = blockIdx.y * 128, col0 = blockIdx.x * 128;
    const bf16_t* A  = kTc + (size_t)lbh * 393216;
    const bf16_t* BT = vTc + (size_t)lbh * 393216;
    f32x4 acc[4][4];
    gemm128_bt(A, 1024, BT, 1024, 1024, row0, col0, As, Bs, acc);

    const int lane = threadIdx.x & 63, wid = threadIdx.x >> 6;
    const int wr = wid >> 1, wc = wid & 1;
    float* ss = ssum + (size_t)h * 147456;
#pragma unroll
    for (int m = 0; m < 4; ++m) {
#pragma unroll
        for (int r = 0; r < 4; ++r) {
            const int d = row0 + wr * 64 + m * 16 + (lane >> 4) * 4 + r;
            const float sc = 1.f / (ksum_c[(size_t)lbh * 384 + d] + 1e-6f);
#pragma unroll
            for (int n = 0; n < 4; ++n) {
                const int e = col0 + wc * 64 + n * 16 + (lane & 15);
                atomicAdd(&ss[(size_t)d * 384 + e], acc[m][n][r] * sc);
            }
        }
    }
}

// mem_new[h,d,e] = bf16(0.95*mem + (0.05*wmean[h]/8)*ssum) — elementwise
__global__ void kmemupd_ew(const float* __restrict__ mem, const float* __restrict__ ssum,
                           const float* __restrict__ wmean, bf16_t* __restrict__ mem_new)
{
    const int idx = blockIdx.x * 256 + threadIdx.x;    // 1179648 total
    const int h = idx / 147456;
    const float wm = wmean[h] * (0.05f / 8.f);
    mem_new[idx] = (bf16_t)(0.95f * mem[idx] + wm * ssum[idx]);
}

// G GEMM: per head, GT[c, h*384+d] = sum_e w_outT[c, h*384+e] * mem_new[h,d,e]
__global__ void __launch_bounds__(256) kgemm_G(
    const bf16_t* __restrict__ w_outT, const bf16_t* __restrict__ mem_new,
    bf16_t* __restrict__ GT)
{
    __shared__ __align__(16) bf16_t As[4096], Bs[4096];
    const int h = blockIdx.z;
    const int row0 = blockIdx.y * 128, col0 = blockIdx.x * 128;   // row=c, col=d
    f32x4 acc[4][4];
    gemm128_bt(w_outT + h * 384, 3072, mem_new + (size_t)h * 147456, 384,
               384, row0, col0, As, Bs, acc);

    const int lane = threadIdx.x & 63, wid = threadIdx.x >> 6;
    const int wr = wid >> 1, wc = wid & 1;
#pragma unroll
    for (int m = 0; m < 4; ++m) {
#pragma unroll
        for (int n = 0; n < 4; ++n) {
            const int d = col0 + wc * 64 + n * 16 + (lane & 15);
#pragma unroll
            for (int r = 0; r < 4; ++r) {
                const int c = row0 + wr * 64 + m * 16 + (lane >> 4) * 4 + r;
                GT[(size_t)c * 3072 + h * 384 + d] = (bf16_t)acc[m][n][r];
            }
        }
    }
}

// out GEMM: C = q~ @ GT^T + b_out; out = residue*C + (1-residue)*x
__global__ void __launch_bounds__(256) kgemm_out(
    const bf16_t* __restrict__ qf, const bf16_t* __restrict__ GT,
    const float* __restrict__ b_out, const float* __restrict__ residue,
    const float* __restrict__ x, float* __restrict__ out)
{
    __shared__ __align__(16) bf16_t As[4096], Bs[4096];
    int bx, by;
    band_map(blockIdx.y * 6 + blockIdx.x, 64, bx, by);
    const int row0 = by * 128, col0 = bx * 128;
    f32x4 acc[4][4];
    gemm128_bt(qf, 3072, GT, 3072, 3072, row0, col0, As, Bs, acc);

    const int lane = threadIdx.x & 63, wid = threadIdx.x >> 6;
    const int wr = wid >> 1, wc = wid & 1;
#pragma unroll
    for (int m = 0; m < 4; ++m) {
#pragma unroll
        for (int n = 0; n < 4; ++n) {
            const int col = col0 + wc * 64 + n * 16 + (lane & 15);
            const float bias = b_out[col];
#pragma unroll
            for (int r = 0; r < 4; ++r) {
                const int row = row0 + wr * 64 + m * 16 + (lane >> 4) * 4 + r;
                const float v = acc[m][n][r] + bias;
                const float rr = residue[row];
                out[(size_t)row * 768 + col] = rr * v + (1.f - rr) * x[(size_t)row * 768 + col];
            }
        }
    }
}

// ---------------------------------------------------------------------------
extern "C" void kernel_launch(void* const* d_in, const int* in_sizes, int n_in,
                              void* d_out, int out_size, void* d_ws, size_t ws_size,
                              hipStream_t stream)
{
    (void)in_sizes; (void)n_in; (void)out_size;
    const float* x     = (const float*)d_in[0];
    const float* mem   = (const float*)d_in[1];
    const float* ln_g  = (const float*)d_in[2];
    const float* ln_b  = (const float*)d_in[3];
    const float* w_in  = (const float*)d_in[4];
    const float* b_in  = (const float*)d_in[5];
    const float* w_out = (const float*)d_in[6];
    const float* b_out = (const float*)d_in[7];
    const float* w_rg  = (const float*)d_in[8];
    const float* b_rg  = (const float*)d_in[9];
    const float* w_wg  = (const float*)d_in[10];
    const float* b_wg  = (const float*)d_in[11];
    const float* w_res = (const float*)d_in[12];
    const float* b_res = (const float*)d_in[13];
    float* out = (float*)d_out;

    auto total_for = [&](int c) -> size_t {
        size_t o = 0;
        auto a = [&](size_t b) { o += (b + 255) & ~(size_t)255; };
        a(50331648);                       // qf
        a(14155776); a(12582912);          // w_inT (GT overlays), xn
        a((size_t)c * 6291456);            // kTc
        a((size_t)c * 6291456);            // vTc
        a(4718592); a(4718592); a(2359296);// w_outT, ssum, mem_new
        a(32768); a(24576); a(98304); a(256); a(256);
        return o;
    };
    int CHUNK = 0;
    for (int c = 8; c >= 2; c >>= 1) if (total_for(c) <= ws_size) { CHUNK = c; break; }
    if (CHUNK == 0) return;                // fail soft

    char* ws = (char*)d_ws;
    size_t off = 0;
    auto alloc = [&](size_t bytes) -> char* {
        char* p = ws + off; off += (bytes + 255) & ~(size_t)255; return p;
    };
    bf16_t* qf      = (bf16_t*)alloc(50331648);
    bf16_t* w_inT   = (bf16_t*)alloc(14155776);
    bf16_t* GT      = w_inT;                 // overlay: w_inT dead after qkv chunks
    bf16_t* xn      = (bf16_t*)alloc(12582912);
    bf16_t* kTc     = (bf16_t*)alloc((size_t)CHUNK * 6291456);
    bf16_t* vTc     = (bf16_t*)alloc((size_t)CHUNK * 6291456);
    bf16_t* w_outT  = (bf16_t*)alloc(4718592);
    float*  ssum    = (float*) alloc(4718592);
    bf16_t* mem_new = (bf16_t*)alloc(2359296);
    float*  residue = (float*) alloc(32768);
    float*  xmean   = (float*) alloc(24576);
    float*  ksum    = (float*) alloc(98304);
    float*  read_g  = (float*) alloc(256);
    float*  wmean   = (float*) alloc(256);

    hipMemsetAsync(xmean, 0, 24576, stream);
    hipMemsetAsync(ksum,  0, 98304, stream);
    hipMemsetAsync(ssum,  0, 4718592, stream);

    ktrans_w<<<dim3(288, 24), dim3(32, 8), 0, stream>>>(w_in, w_inT, 768, 9216);
    ktrans_w<<<dim3(24, 96), dim3(32, 8), 0, stream>>>(w_out, w_outT, 3072, 768);
    kln<<<8192, 256, 0, stream>>>(x, ln_g, ln_b, w_res, b_res, xn, residue);
    kcolmean<<<dim3(8, 3, 8), 256, 0, stream>>>(xn, xmean);
    kgates<<<1, 256, 0, stream>>>(xmean, w_rg, b_rg, w_wg, b_wg, read_g, wmean);

    const int NC = 8 / CHUNK;
    for (int c = 0; c < NC; ++c) {
        const int b0 = c * CHUNK;
        kgemm_qkv256<<<dim3(36, CHUNK * 4), 512, 0, stream>>>(
            xn + (size_t)b0 * 1024 * 768, w_inT, b_in, read_g + b0 * 8,
            qf + (size_t)b0 * 1024 * 3072, kTc, vTc,
            ksum + (size_t)b0 * 8 * 384, CHUNK * 4);
        kgemm_state<<<dim3(3, 3, CHUNK * 8), 256, 0, stream>>>(
            kTc, vTc, ksum + (size_t)b0 * 8 * 384, ssum);
    }

    kmemupd_ew<<<4608, 256, 0, stream>>>(mem, ssum, wmean, mem_new);
    kgemm_G<<<dim3(3, 6, 8), 256, 0, stream>>>(w_outT, mem_new, GT);
    kgemm_out<<<dim3(6, 64), 256, 0, stream>>>(qf, GT, b_out, residue, x, out);
}